// Round 17
// baseline (96.804 us; speedup 1.0000x reference)
//
#include <hip/hip_runtime.h>

#define NATOMS 8192
#define DD 128     // embedding dim
#define HH 256     // hidden dim
#define TI 4       // atoms per block in aggregation -- FROZEN (TI=8 fails: R7/R11)
#define MAXE 128   // max edges per atom (mean ~20, Poisson; 128 is >>6 sigma)
#define BM 32      // nodes per block in MFMA MLP
#define KJ2KCAL 0.2390057361376673f

typedef __attribute__((ext_vector_type(8))) short bf16x8;  // 4 VGPRs
typedef __attribute__((ext_vector_type(4))) float f32x4;

// fp32 -> bf16 round-to-nearest-even (finite inputs)
__device__ inline unsigned short f2bf(float x) {
  unsigned int b = __builtin_bit_cast(unsigned int, x);
  b += 0x7FFFu + ((b >> 16) & 1u);
  return (unsigned short)(b >> 16);
}

// k_agg [verbatim R10 98.2us-verified source: merged prep + ballot sweep +
// unroll4; pk-packing reverted (R13 null)]. TI=4 frozen.
__global__ __launch_bounds__(256) void k_agg(const float* __restrict__ pos,
                                             const int* __restrict__ types,
                                             const float* __restrict__ W1,
                                             const float* __restrict__ emb,
                                             unsigned short* __restrict__ W1bfT,
                                             unsigned short* __restrict__ aggbf,
                                             float* __restrict__ out) {
  __shared__ unsigned long long smask[TI][NATOMS / 64];  // 4 KB
  __shared__ float sw[TI][MAXE];
  __shared__ int   srow[TI][MAXE];
  __shared__ int   scnt[TI];
  const int tid = threadIdx.x;
  const int i0 = blockIdx.x * TI;

  // merged one-time prep (identical values to verified k_prep)
  if (blockIdx.x < 64) {
    int t = blockIdx.x * 256 + tid;         // 0..16383
    if (t == 0) out[0] = 0.0f;
    int n = t & 255;
    int kb = (t >> 8) * 4;                  // 0,4,..,252
#pragma unroll
    for (int i = 0; i < 4; ++i)
      W1bfT[n * HH + kb + i] = f2bf(W1[(kb + i) * HH + n]);  // read coalesced in n
  }

  float pix[TI], piy[TI], piz[TI];
#pragma unroll
  for (int m = 0; m < TI; ++m) {   // uniform addresses -> scalar loads
    pix[m] = 10.0f * pos[(i0 + m) * 3 + 0];
    piy[m] = 10.0f * pos[(i0 + m) * 3 + 1];
    piz[m] = 10.0f * pos[(i0 + m) * 3 + 2];
  }

  // sweep: lanes of a wave cover 64 consecutive j -> ballot bit r <-> j=64c+r
#pragma unroll 4
  for (int j = tid; j < NATOMS; j += 256) {
    float pjx = 10.0f * pos[j * 3 + 0];
    float pjy = 10.0f * pos[j * 3 + 1];
    float pjz = 10.0f * pos[j * 3 + 2];
    int c = j >> 6;                // wave-uniform chunk id
#pragma unroll
    for (int m = 0; m < TI; ++m) {
      float dx = pix[m] - pjx, dy = piy[m] - pjy, dz = piz[m] - pjz;
      float d2 = dx * dx;
      d2 = fmaf(dy, dy, d2);
      d2 = fmaf(dz, dz, d2);
      // ref mask: d2 > 1e-12 && sqrt(d2) <= 5  <=>  1e-12 < d2 <= 25 (fp32-exact)
      unsigned long long bal = __ballot(d2 > 1e-12f && d2 <= 25.0f);
      if ((tid & 63) == 0) smask[m][c] = bal;
    }
  }
  __syncthreads();

  // scan + expand: wave m handles atom m. Lane l owns chunks {2l, 2l+1}.
  {
    const int m = tid >> 6;        // 0..3 (4 waves)
    const int l = tid & 63;
    unsigned long long mA = smask[m][2 * l];
    unsigned long long mB = smask[m][2 * l + 1];
    int cA = __popcll(mA), cB = __popcll(mB);
    int s = cA + cB;
    int scan = s;                  // inclusive prefix over 64 lanes
#pragma unroll
    for (int off = 1; off < 64; off <<= 1) {
      int t = __shfl_up(scan, off);
      if (l >= off) scan += t;
    }
    int excl = scan - s;
    if (l == 63) scnt[m] = scan;   // per-atom total
    float px = 10.0f * pos[(i0 + m) * 3 + 0];
    float py = 10.0f * pos[(i0 + m) * 3 + 1];
    float pz = 10.0f * pos[(i0 + m) * 3 + 2];
#pragma unroll
    for (int h = 0; h < 2; ++h) {
      unsigned long long mask = h ? mB : mA;
      int base = h ? excl + cA : excl;
      int cbase = 64 * (2 * l + h);
      while (mask) {
        int r = __ffsll((long long)mask) - 1;
        mask &= mask - 1;
        int j = cbase + r;
        if (base < MAXE) {
          float pjx = 10.0f * pos[j * 3 + 0];
          float pjy = 10.0f * pos[j * 3 + 1];
          float pjz = 10.0f * pos[j * 3 + 2];
          float dx = px - pjx, dy = py - pjy, dz = pz - pjz;
          float d2 = dx * dx;
          d2 = fmaf(dy, dy, d2);
          d2 = fmaf(dz, dz, d2);
          float w = __expf(-sqrtf(d2));
          sw[m][base] = w;
          srow[m][base] = types[j] * DD;
        }
        ++base;
      }
    }
  }
  __syncthreads();

  // phase 2 [verbatim R10]: 2 groups of 128 dims; group g -> atoms {g, g+2}
  const int d = tid & (DD - 1);
  const int g = tid >> 7;
#pragma unroll
  for (int mm = 0; mm < TI; mm += 2) {
    int m = g + mm;
    int nc = min(scnt[m], MAXE);
    float a = 0.0f;
#pragma unroll 4
    for (int e = 0; e < nc; ++e)
      a = fmaf(sw[m][e], emb[srow[m][e] + d], a);
    aggbf[(size_t)(i0 + m) * DD + d] = f2bf(a);   // feat is bf16 downstream anyway
  }
}

// MFMA MLP [R10-verified except the LAST STEP]: hidden = feat @ W1 (bf16 in,
// f32 acc), then sum(relu(hidden)*w2). The 256-block single-address
// atomicAdd(out) tail is replaced by a per-block partial store (part[bid]);
// same per-block value, same scaling expression. Theory: 256 serialized
// same-address L2 atomics were the ~20us invisible tail (explains R0-R3's
// k_mlp invariance at VALUBusy 17%).
__global__ __launch_bounds__(512, 2) void k_mlp(const int* __restrict__ types,
                                                const float* __restrict__ emb,
                                                const unsigned short* __restrict__ aggbf,
                                                const unsigned short* __restrict__ W1bfT,
                                                const float* __restrict__ w2,
                                                float* __restrict__ part) {
  __shared__ unsigned short sA[BM][264];  // 16.5 KB
  __shared__ float sred[8];
  const int tid = threadIdx.x;
  const int n0 = blockIdx.x * BM;

  // stage feat = concat(emb[type], aggbf) as bf16: 32 rows x 64 chunks of 4
  for (int idx = tid; idx < BM * 64; idx += 512) {
    int row = idx >> 6;
    int cb = idx & 63;          // 4-col chunk
    int node = n0 + row;
    ushort4 u;
    if (cb < 32) {
      float4 v = *(const float4*)&emb[types[node] * DD + 4 * cb];
      u.x = f2bf(v.x); u.y = f2bf(v.y); u.z = f2bf(v.z); u.w = f2bf(v.w);
    } else {
      u = *(const ushort4*)&aggbf[(size_t)node * DD + 4 * (cb - 32)];
    }
    *(ushort4*)&sA[row][4 * cb] = u;
  }
  __syncthreads();

  const int lane = tid & 63;
  const int wv = tid >> 6;      // 0..7 -> N-slice
  const int nb = wv * 32;
  const int l15 = lane & 15;
  const int g = lane >> 4;      // 0..3 -> k-subgroup
  f32x4 acc00 = {}, acc01 = {}, acc10 = {}, acc11 = {};

  const unsigned short* bp0 = W1bfT + (nb + l15) * HH + 8 * g;
  const unsigned short* bp1 = bp0 + 16 * HH;
#pragma unroll
  for (int ks = 0; ks < 8; ++ks) {
    bf16x8 a0 = *(const bf16x8*)&sA[l15][ks * 32 + 8 * g];
    bf16x8 a1 = *(const bf16x8*)&sA[16 + l15][ks * 32 + 8 * g];
    bf16x8 b0 = *(const bf16x8*)(bp0 + ks * 32);
    bf16x8 b1 = *(const bf16x8*)(bp1 + ks * 32);
    acc00 = __builtin_amdgcn_mfma_f32_16x16x32_bf16(a0, b0, acc00, 0, 0, 0);
    acc01 = __builtin_amdgcn_mfma_f32_16x16x32_bf16(a0, b1, acc01, 0, 0, 0);
    acc10 = __builtin_amdgcn_mfma_f32_16x16x32_bf16(a1, b0, acc10, 0, 0, 0);
    acc11 = __builtin_amdgcn_mfma_f32_16x16x32_bf16(a1, b1, acc11, 0, 0, 0);
  }

  const float w2a = w2[nb + l15];
  const float w2b = w2[nb + 16 + l15];
  float p = 0.0f;
#pragma unroll
  for (int i = 0; i < 4; ++i) {
    p += fmaxf(acc00[i], 0.0f) * w2a;
    p += fmaxf(acc10[i], 0.0f) * w2a;
    p += fmaxf(acc01[i], 0.0f) * w2b;
    p += fmaxf(acc11[i], 0.0f) * w2b;
  }
#pragma unroll
  for (int off = 32; off; off >>= 1) p += __shfl_down(p, off);  // wave64 reduce
  if (lane == 0) sred[wv] = p;
  __syncthreads();
  if (tid == 0) {
    float t = 0.0f;
#pragma unroll
    for (int q = 0; q < 8; ++q) t += sred[q];
    part[blockIdx.x] = t * KJ2KCAL;   // plain store, no contention
  }
}

// Final reduce: 1 block, 64 threads, sums the 256 per-block partials and
// writes the output scalar directly (overwrites the poison).
__global__ void k_fin(const float* __restrict__ part, float* __restrict__ out) {
  int l = threadIdx.x;   // 0..63
  float s = part[l] + part[l + 64] + part[l + 128] + part[l + 192];
#pragma unroll
  for (int off = 32; off; off >>= 1) s += __shfl_down(s, off);
  if (l == 0) out[0] = s;
}

extern "C" void kernel_launch(void* const* d_in, const int* in_sizes, int n_in,
                              void* d_out, int out_size, void* d_ws, size_t ws_size,
                              hipStream_t stream) {
  const float* pos = (const float*)d_in[0];
  const int*   typ = (const int*)d_in[1];
  const float* emb = (const float*)d_in[2];
  const float* W1  = (const float*)d_in[3];
  const float* w2  = (const float*)d_in[4];
  float* out = (float*)d_out;
  unsigned short* aggbf = (unsigned short*)d_ws;                        // 2 MB
  unsigned short* W1bfT = (unsigned short*)((char*)d_ws + (2u << 20));  // 128 KB
  float*          part  = (float*)((char*)d_ws + (4u << 20));           // 1 KB

  hipLaunchKernelGGL(k_agg, dim3(NATOMS / TI), dim3(256), 0, stream,
                     pos, typ, W1, emb, W1bfT, aggbf, out);
  hipLaunchKernelGGL(k_mlp, dim3(NATOMS / BM), dim3(512), 0, stream,
                     typ, emb, aggbf, W1bfT, w2, part);
  hipLaunchKernelGGL(k_fin, dim3(1), dim3(64), 0, stream, part, out);
}

// Round 18
// 95.970 us; speedup vs baseline: 1.0087x; 1.0087x over previous
//
#include <hip/hip_runtime.h>

#define NATOMS 8192
#define DD 128     // embedding dim
#define HH 256     // hidden dim
#define TI 4       // atoms per block in aggregation -- FROZEN (TI=8 fails: R7/R11)
#define MAXE 128   // max edges per atom (mean ~20, Poisson; 128 is >>6 sigma)
#define BM 32      // nodes per block in MFMA MLP
#define KJ2KCAL 0.2390057361376673f

typedef __attribute__((ext_vector_type(8))) short bf16x8;  // 4 VGPRs
typedef __attribute__((ext_vector_type(4))) float f32x4;

// fp32 -> bf16 round-to-nearest-even (finite inputs)
__device__ inline unsigned short f2bf(float x) {
  unsigned int b = __builtin_bit_cast(unsigned int, x);
  b += 0x7FFFu + ((b >> 16) & 1u);
  return (unsigned short)(b >> 16);
}

// k_agg [R17-verified source; ONLY change: the three scalar position loads
// per j become one float3 deref (global_load_dwordx3) -- same 12 bytes, same
// 10.0f* multiplies, bit-identical d2/mask/weights. R12 counters showed the
// sweep is VALU/issue-bound (55% busy, 1% HBM); this removes ~8 issue slots
// (2 loads + addr calc) of ~70 per j-iteration.] TI=4 frozen.
__global__ __launch_bounds__(256) void k_agg(const float* __restrict__ pos,
                                             const int* __restrict__ types,
                                             const float* __restrict__ W1,
                                             const float* __restrict__ emb,
                                             unsigned short* __restrict__ W1bfT,
                                             unsigned short* __restrict__ aggbf,
                                             float* __restrict__ out) {
  __shared__ unsigned long long smask[TI][NATOMS / 64];  // 4 KB
  __shared__ float sw[TI][MAXE];
  __shared__ int   srow[TI][MAXE];
  __shared__ int   scnt[TI];
  const int tid = threadIdx.x;
  const int i0 = blockIdx.x * TI;

  // merged one-time prep (identical values to verified k_prep)
  if (blockIdx.x < 64) {
    int t = blockIdx.x * 256 + tid;         // 0..16383
    if (t == 0) out[0] = 0.0f;
    int n = t & 255;
    int kb = (t >> 8) * 4;                  // 0,4,..,252
#pragma unroll
    for (int i = 0; i < 4; ++i)
      W1bfT[n * HH + kb + i] = f2bf(W1[(kb + i) * HH + n]);  // read coalesced in n
  }

  float pix[TI], piy[TI], piz[TI];
#pragma unroll
  for (int m = 0; m < TI; ++m) {   // uniform addresses -> scalar loads
    pix[m] = 10.0f * pos[(i0 + m) * 3 + 0];
    piy[m] = 10.0f * pos[(i0 + m) * 3 + 1];
    piz[m] = 10.0f * pos[(i0 + m) * 3 + 2];
  }

  // sweep: lanes of a wave cover 64 consecutive j -> ballot bit r <-> j=64c+r
#pragma unroll 4
  for (int j = tid; j < NATOMS; j += 256) {
    float3 pj = *(const float3*)&pos[3 * j];   // one dwordx3, same 12 bytes
    float pjx = 10.0f * pj.x;
    float pjy = 10.0f * pj.y;
    float pjz = 10.0f * pj.z;
    int c = j >> 6;                // wave-uniform chunk id
#pragma unroll
    for (int m = 0; m < TI; ++m) {
      float dx = pix[m] - pjx, dy = piy[m] - pjy, dz = piz[m] - pjz;
      float d2 = dx * dx;
      d2 = fmaf(dy, dy, d2);
      d2 = fmaf(dz, dz, d2);
      // ref mask: d2 > 1e-12 && sqrt(d2) <= 5  <=>  1e-12 < d2 <= 25 (fp32-exact)
      unsigned long long bal = __ballot(d2 > 1e-12f && d2 <= 25.0f);
      if ((tid & 63) == 0) smask[m][c] = bal;
    }
  }
  __syncthreads();

  // scan + expand: wave m handles atom m. Lane l owns chunks {2l, 2l+1}.
  {
    const int m = tid >> 6;        // 0..3 (4 waves)
    const int l = tid & 63;
    unsigned long long mA = smask[m][2 * l];
    unsigned long long mB = smask[m][2 * l + 1];
    int cA = __popcll(mA), cB = __popcll(mB);
    int s = cA + cB;
    int scan = s;                  // inclusive prefix over 64 lanes
#pragma unroll
    for (int off = 1; off < 64; off <<= 1) {
      int t = __shfl_up(scan, off);
      if (l >= off) scan += t;
    }
    int excl = scan - s;
    if (l == 63) scnt[m] = scan;   // per-atom total
    float px = 10.0f * pos[(i0 + m) * 3 + 0];
    float py = 10.0f * pos[(i0 + m) * 3 + 1];
    float pz = 10.0f * pos[(i0 + m) * 3 + 2];
#pragma unroll
    for (int h = 0; h < 2; ++h) {
      unsigned long long mask = h ? mB : mA;
      int base = h ? excl + cA : excl;
      int cbase = 64 * (2 * l + h);
      while (mask) {
        int r = __ffsll((long long)mask) - 1;
        mask &= mask - 1;
        int j = cbase + r;
        if (base < MAXE) {
          float3 pjv = *(const float3*)&pos[3 * j];   // same bytes, one load
          float pjx = 10.0f * pjv.x;
          float pjy = 10.0f * pjv.y;
          float pjz = 10.0f * pjv.z;
          float dx = px - pjx, dy = py - pjy, dz = pz - pjz;
          float d2 = dx * dx;
          d2 = fmaf(dy, dy, d2);
          d2 = fmaf(dz, dz, d2);
          float w = __expf(-sqrtf(d2));
          sw[m][base] = w;
          srow[m][base] = types[j] * DD;
        }
        ++base;
      }
    }
  }
  __syncthreads();

  // phase 2 [verbatim R10]: 2 groups of 128 dims; group g -> atoms {g, g+2}
  const int d = tid & (DD - 1);
  const int g = tid >> 7;
#pragma unroll
  for (int mm = 0; mm < TI; mm += 2) {
    int m = g + mm;
    int nc = min(scnt[m], MAXE);
    float a = 0.0f;
#pragma unroll 4
    for (int e = 0; e < nc; ++e)
      a = fmaf(sw[m][e], emb[srow[m][e] + d], a);
    aggbf[(size_t)(i0 + m) * DD + d] = f2bf(a);   // feat is bf16 downstream anyway
  }
}

// MFMA MLP [verbatim R14/R17]: hidden = feat @ W1 (bf16 in, f32 acc), then
// sum(relu(hidden)*w2) -> per-block partial store (no atomic contention).
__global__ __launch_bounds__(512, 2) void k_mlp(const int* __restrict__ types,
                                                const float* __restrict__ emb,
                                                const unsigned short* __restrict__ aggbf,
                                                const unsigned short* __restrict__ W1bfT,
                                                const float* __restrict__ w2,
                                                float* __restrict__ part) {
  __shared__ unsigned short sA[BM][264];  // 16.5 KB
  __shared__ float sred[8];
  const int tid = threadIdx.x;
  const int n0 = blockIdx.x * BM;

  // stage feat = concat(emb[type], aggbf) as bf16: 32 rows x 64 chunks of 4
  for (int idx = tid; idx < BM * 64; idx += 512) {
    int row = idx >> 6;
    int cb = idx & 63;          // 4-col chunk
    int node = n0 + row;
    ushort4 u;
    if (cb < 32) {
      float4 v = *(const float4*)&emb[types[node] * DD + 4 * cb];
      u.x = f2bf(v.x); u.y = f2bf(v.y); u.z = f2bf(v.z); u.w = f2bf(v.w);
    } else {
      u = *(const ushort4*)&aggbf[(size_t)node * DD + 4 * (cb - 32)];
    }
    *(ushort4*)&sA[row][4 * cb] = u;
  }
  __syncthreads();

  const int lane = tid & 63;
  const int wv = tid >> 6;      // 0..7 -> N-slice
  const int nb = wv * 32;
  const int l15 = lane & 15;
  const int g = lane >> 4;      // 0..3 -> k-subgroup
  f32x4 acc00 = {}, acc01 = {}, acc10 = {}, acc11 = {};

  const unsigned short* bp0 = W1bfT + (nb + l15) * HH + 8 * g;
  const unsigned short* bp1 = bp0 + 16 * HH;
#pragma unroll
  for (int ks = 0; ks < 8; ++ks) {
    bf16x8 a0 = *(const bf16x8*)&sA[l15][ks * 32 + 8 * g];
    bf16x8 a1 = *(const bf16x8*)&sA[16 + l15][ks * 32 + 8 * g];
    bf16x8 b0 = *(const bf16x8*)(bp0 + ks * 32);
    bf16x8 b1 = *(const bf16x8*)(bp1 + ks * 32);
    acc00 = __builtin_amdgcn_mfma_f32_16x16x32_bf16(a0, b0, acc00, 0, 0, 0);
    acc01 = __builtin_amdgcn_mfma_f32_16x16x32_bf16(a0, b1, acc01, 0, 0, 0);
    acc10 = __builtin_amdgcn_mfma_f32_16x16x32_bf16(a1, b0, acc10, 0, 0, 0);
    acc11 = __builtin_amdgcn_mfma_f32_16x16x32_bf16(a1, b1, acc11, 0, 0, 0);
  }

  const float w2a = w2[nb + l15];
  const float w2b = w2[nb + 16 + l15];
  float p = 0.0f;
#pragma unroll
  for (int i = 0; i < 4; ++i) {
    p += fmaxf(acc00[i], 0.0f) * w2a;
    p += fmaxf(acc10[i], 0.0f) * w2a;
    p += fmaxf(acc01[i], 0.0f) * w2b;
    p += fmaxf(acc11[i], 0.0f) * w2b;
  }
#pragma unroll
  for (int off = 32; off; off >>= 1) p += __shfl_down(p, off);  // wave64 reduce
  if (lane == 0) sred[wv] = p;
  __syncthreads();
  if (tid == 0) {
    float t = 0.0f;
#pragma unroll
    for (int q = 0; q < 8; ++q) t += sred[q];
    part[blockIdx.x] = t * KJ2KCAL;   // plain store, no contention
  }
}

// Final reduce [verbatim R14/R17]: sums 256 partials, writes the output scalar.
__global__ void k_fin(const float* __restrict__ part, float* __restrict__ out) {
  int l = threadIdx.x;   // 0..63
  float s = part[l] + part[l + 64] + part[l + 128] + part[l + 192];
#pragma unroll
  for (int off = 32; off; off >>= 1) s += __shfl_down(s, off);
  if (l == 0) out[0] = s;
}

extern "C" void kernel_launch(void* const* d_in, const int* in_sizes, int n_in,
                              void* d_out, int out_size, void* d_ws, size_t ws_size,
                              hipStream_t stream) {
  const float* pos = (const float*)d_in[0];
  const int*   typ = (const int*)d_in[1];
  const float* emb = (const float*)d_in[2];
  const float* W1  = (const float*)d_in[3];
  const float* w2  = (const float*)d_in[4];
  float* out = (float*)d_out;
  unsigned short* aggbf = (unsigned short*)d_ws;                        // 2 MB
  unsigned short* W1bfT = (unsigned short*)((char*)d_ws + (2u << 20));  // 128 KB
  float*          part  = (float*)((char*)d_ws + (4u << 20));           // 1 KB

  hipLaunchKernelGGL(k_agg, dim3(NATOMS / TI), dim3(256), 0, stream,
                     pos, typ, W1, emb, W1bfT, aggbf, out);
  hipLaunchKernelGGL(k_mlp, dim3(NATOMS / BM), dim3(512), 0, stream,
                     typ, emb, aggbf, W1bfT, w2, part);
  hipLaunchKernelGGL(k_fin, dim3(1), dim3(64), 0, stream, part, out);
}